// Round 12
// baseline (93.419 us; speedup 1.0000x reference)
//
#include <hip/hip_runtime.h>

#define VV 100000
#define NN 20000
#define KK 32
#define DD 256
#define HH 256
#define BN 16   // nodes per block in fused kernels

#if __has_builtin(__builtin_amdgcn_global_load_lds)
#define HAS_GLL 1
#else
#define HAS_GLL 0
#endif

typedef __attribute__((ext_vector_type(8))) short bf16x8;
typedef __attribute__((ext_vector_type(4))) float f32x4;
typedef __attribute__((ext_vector_type(2))) float f32x2;
typedef __attribute__((ext_vector_type(4))) uint  u32x4;
typedef __attribute__((ext_vector_type(2))) uint  u32x2;

__device__ __forceinline__ ushort f2bf(float f) {
    // round-to-nearest-even f32 -> bf16
    uint u = __float_as_uint(f);
    return (ushort)((u + 0x7FFFu + ((u >> 16) & 1u)) >> 16);
}
__device__ __forceinline__ float bf2f(ushort u) {
    return __uint_as_float(((uint)u) << 16);
}

// ------- Kernel 1 (merged): embed f32->fp8 table + W transpose to bf16 -----
// blocks [0,6250): conv8 (16 elems/thread); blocks [6250,6282): W prep.
__global__ __launch_bounds__(256) void k_prep_all(
    const float* __restrict__ E,  unsigned char* __restrict__ E8,
    const float* __restrict__ Ws, const float* __restrict__ Wn,
    ushort* __restrict__ WT)   // [2][H][D] bf16
{
    __shared__ float t[64][65];
    const int tid = threadIdx.x;
    const int bx  = blockIdx.x;

    if (bx < 6250) {
        const size_t i = ((size_t)bx * 256 + tid) * 16;
        u32x4 o;
        #pragma unroll
        for (int w = 0; w < 4; ++w) {
            const f32x4 a = __builtin_nontemporal_load((const f32x4*)&E[i + w * 4]);
            int r = 0;
            r = __builtin_amdgcn_cvt_pk_fp8_f32(a.x, a.y, r, false);
            r = __builtin_amdgcn_cvt_pk_fp8_f32(a.z, a.w, r, true);
            o[w] = (uint)r;
        }
        *(u32x4*)&E8[i] = o;
        return;
    }

    const int pb = bx - 6250;          // 0..31
    const int z  = pb >> 4;            // 0 = Ws, 1 = Wn
    const int rem = pb & 15;
    const int d0 = (rem & 3) * 64, h0 = (rem >> 2) * 64;
    const float* src = z ? Wn : Ws;
    ushort* dst = WT + (size_t)z * HH * DD;

    const int hl = tid & 63, dq = tid >> 6;
    #pragma unroll
    for (int i = 0; i < 16; ++i) {
        const int dl = dq * 16 + i;
        t[dl][hl] = src[(size_t)(d0 + dl) * HH + h0 + hl];
    }
    __syncthreads();
    const int dl = tid & 63, hq = tid >> 6;
    #pragma unroll
    for (int i = 0; i < 16; ++i) {
        const int h2 = hq * 16 + i;
        dst[(size_t)(h0 + h2) * DD + d0 + dl] = f2bf(t[dl][h2]);
    }
}

#if HAS_GLL
// ------- Kernel 2: fused gather via global_load_lds + pool + MFMA GEMM -----
// 256 thr = 4 waves, BN=16 nodes, grid 1250.
// Phase 1: per wave, 4 nodes sequentially. Per node: 32 neighbor fp8 rows
//   streamed to LDS stage via global_load_lds width-4 (64 lanes x 4 B = one
//   256-B row per instruction; ZERO VGPRs for the 32-deep window — this is
//   what rounds 6/10 lacked). Self row f32 via 2 register loads. vmcnt(0),
//   then pool: lane owns elems [4*lane,+4): 32 ds_read_b32 (2-way bank, free)
//   + cvt_pk_f32_fp8. Store bf16 to XOR-swizzled As/An.
// Phase 2: byte-identical round-6 proven MFMA (half=wv>>1, colq=(wv&1)*128).
// LDS: stage 32 KB + As/An 16 KB = 48 KB -> 3 blocks/CU, 12 waves/CU.
__global__ __launch_bounds__(256, 3) void k_fusedgl(
    const float*         __restrict__ Ef,
    const unsigned char* __restrict__ E8,
    const int*           __restrict__ node_ids,
    const int*           __restrict__ nb_ids,
    const ushort*        __restrict__ WT,    // [2][H][D] bf16
    const float*         __restrict__ bias,  // [2H]
    float*               __restrict__ out)   // [N][2H]
{
    __shared__ unsigned char stage[4][KK * 256];  // 32 KB
    __shared__ ushort As[BN][DD];                 // 8 KB
    __shared__ ushort An[BN][DD];                 // 8 KB
    const int tid  = threadIdx.x;
    const int wv   = tid >> 6;
    const int lane = tid & 63;
    const int sub  = lane >> 5, l31 = lane & 31;
    const int g0   = blockIdx.x * BN;

    // ---- Phase 1 ----
    for (int it = 0; it < 4; ++it) {
        const int n = wv + it * 4;
        const int g = g0 + n;
        const int base = g * KK;

        // self row f32 (register path; both halves load, lo half stores)
        const int srow = node_ids[g];    // uniform -> s_load
        const f32x4 s0 = *(const f32x4*)&Ef[(size_t)(uint)srow * DD + l31 * 8];
        const f32x4 s1 = *(const f32x4*)&Ef[(size_t)(uint)srow * DD + l31 * 8 + 4];

        // 32 neighbor rows -> LDS, async, no VGPR window
        #pragma unroll
        for (int j = 0; j < KK; ++j) {
            const int row = nb_ids[base + j];             // uniform -> s_load
            const unsigned char* gp = E8 + (size_t)(uint)row * DD + lane * 4;
            __builtin_amdgcn_global_load_lds(
                (const __attribute__((address_space(1))) void*)gp,
                (__attribute__((address_space(3))) void*)&stage[wv][j * 256],
                4, 0, 0);
        }
        asm volatile("s_waitcnt vmcnt(0)" ::: "memory");
        __builtin_amdgcn_sched_barrier(0);

        // pool: lane accumulates its 4-element slice [4*lane, 4*lane+4)
        float a0 = 0.f, a1 = 0.f, a2 = 0.f, a3 = 0.f;
        #pragma unroll
        for (int j = 0; j < KK; ++j) {
            const uint w = *(const uint*)&stage[wv][j * 256 + lane * 4];
            const f32x2 lo = __builtin_amdgcn_cvt_pk_f32_fp8((int)w, false);
            const f32x2 hi = __builtin_amdgcn_cvt_pk_f32_fp8((int)w, true);
            a0 += lo.x; a1 += lo.y; a2 += hi.x; a3 += hi.y;
        }
        const float inv = 1.0f / (float)KK;
        const ushort4 nv = make_ushort4(f2bf(a0 * inv), f2bf(a1 * inv),
                                        f2bf(a2 * inv), f2bf(a3 * inv));
        const uint swz = ((uint)(n & 7)) << 4;
        // pooled: 8 B per lane at natural byte offset ^ swz (16B-granular XOR)
        *(ushort4*)((char*)&An[n][0] + ((((uint)lane) * 8) ^ swz)) = nv;
        if (sub == 0) {
            bf16x8 sv;
            sv[0] = (short)f2bf(s0.x); sv[1] = (short)f2bf(s0.y);
            sv[2] = (short)f2bf(s0.z); sv[3] = (short)f2bf(s0.w);
            sv[4] = (short)f2bf(s1.x); sv[5] = (short)f2bf(s1.y);
            sv[6] = (short)f2bf(s1.z); sv[7] = (short)f2bf(s1.w);
            *(bf16x8*)((char*)&As[n][0] + ((((uint)l31) * 16) ^ swz)) = sv;
        }
    }
    __syncthreads();

    // ---- Phase 2 (round-6 proven) ----
    const int half = wv >> 1;
    const int colq = (wv & 1) * 128;
    const int r16  = lane & 15;
    const int kg   = lane >> 4;
    const uint rswz = ((uint)(r16 & 7)) << 4;
    const char* Arow = (const char*)(half ? &An[r16][0] : &As[r16][0]);

    bf16x8 a[8];
    #pragma unroll
    for (int ks = 0; ks < 8; ++ks) {
        const uint off = (uint)(ks * 64 + kg * 16);
        a[ks] = *(const bf16x8*)(Arow + (off ^ rswz));
    }

    const ushort* Wb = WT + (size_t)half * HH * DD;
    f32x4 accs[8];
    #pragma unroll
    for (int ct = 0; ct < 8; ++ct) {
        const int c = colq + ct * 16 + r16;
        const ushort* Bb = Wb + (size_t)c * DD + kg * 8;
        f32x4 acc = {0.f, 0.f, 0.f, 0.f};
        #pragma unroll
        for (int ks = 0; ks < 8; ++ks) {
            const bf16x8 b = *(const bf16x8*)(Bb + ks * 32);
            acc = __builtin_amdgcn_mfma_f32_16x16x32_bf16(a[ks], b, acc, 0, 0, 0);
        }
        accs[ct] = acc;
    }

    #pragma unroll
    for (int ct = 0; ct < 8; ++ct) {
        const int cglob = half * HH + colq + ct * 16 + r16;
        const float bv = bias[cglob];
        #pragma unroll
        for (int r = 0; r < 4; ++r) {
            const float v = accs[ct][r] + bv;
            out[(size_t)(g0 + kg * 4 + r) * (2 * HH) + cglob] = v > 0.f ? v : 0.f;
        }
    }
}
#endif  // HAS_GLL

// ===================== round-11 proven fallback pipeline ====================
__global__ __launch_bounds__(256) void k_conv8(
    const float* __restrict__ E, unsigned char* __restrict__ E8)
{
    const size_t i = ((size_t)blockIdx.x * 256 + threadIdx.x) * 16;
    u32x4 o;
    #pragma unroll
    for (int w = 0; w < 4; ++w) {
        const f32x4 a = __builtin_nontemporal_load((const f32x4*)&E[i + w * 4]);
        int r = 0;
        r = __builtin_amdgcn_cvt_pk_fp8_f32(a.x, a.y, r, false);
        r = __builtin_amdgcn_cvt_pk_fp8_f32(a.z, a.w, r, true);
        o[w] = (uint)r;
    }
    *(u32x4*)&E8[i] = o;
}

__global__ __launch_bounds__(256) void k_prep_wf(
    const float* __restrict__ Ws, const float* __restrict__ Wn,
    ushort* __restrict__ WTf)
{
    __shared__ float t[256][17];
    const int tid = threadIdx.x;
    const int h   = blockIdx.y;
    const int tt  = blockIdx.x;
    const float* src = h ? Wn : Ws;
    const int h0 = tt * 16;
    const int c = tid & 15, dr = tid >> 4;
    #pragma unroll
    for (int s = 0; s < 16; ++s) {
        const int d = s * 16 + dr;
        t[d][c] = src[(size_t)d * HH + h0 + c];
    }
    __syncthreads();
    const int fl = tid & 63, w = tid >> 6;
    const int r16 = fl & 15, kg = fl >> 4;
    #pragma unroll
    for (int p = 0; p < 2; ++p) {
        const int ks = w + p * 4;
        bf16x8 v;
        #pragma unroll
        for (int e = 0; e < 8; ++e)
            v[e] = (short)f2bf(t[ks * 32 + kg * 8 + e][r16]);
        *(bf16x8*)&WTf[(((size_t)(h * 16 + tt) * 8 + ks) * 64 + fl) * 8] = v;
    }
}

__global__ __launch_bounds__(256, 6) void k_gather8(
    const float*         __restrict__ Ef,
    const unsigned char* __restrict__ E8,
    const int*           __restrict__ node_ids,
    const int*           __restrict__ nb_ids,
    ushort*              __restrict__ A)
{
    const int wv   = threadIdx.x >> 6;
    const int lane = threadIdx.x & 63;
    const int sub  = lane >> 5, l31 = lane & 31;
    const int g    = blockIdx.x * 4 + wv;
    const int base = g * KK;

    const int srow = node_ids[g];
    const f32x4 s0 = *(const f32x4*)&Ef[(size_t)(uint)srow * DD + l31 * 8];
    const f32x4 s1 = *(const f32x4*)&Ef[(size_t)(uint)srow * DD + l31 * 8 + 4];

    u32x2 d[16];
    #pragma unroll
    for (int j = 0; j < 16; ++j) {
        const int rlo = nb_ids[base + 2 * j];
        const int rhi = nb_ids[base + 2 * j + 1];
        const int row = sub ? rhi : rlo;
        d[j] = *(const u32x2*)&E8[(size_t)(uint)row * DD + l31 * 8];
    }

    float acc[8];
    #pragma unroll
    for (int e = 0; e < 8; ++e) acc[e] = 0.f;
    #pragma unroll
    for (int j = 0; j < 16; ++j) {
        #pragma unroll
        for (int w = 0; w < 2; ++w) {
            const f32x2 lo = __builtin_amdgcn_cvt_pk_f32_fp8((int)d[j][w], false);
            const f32x2 hi = __builtin_amdgcn_cvt_pk_f32_fp8((int)d[j][w], true);
            acc[w * 4 + 0] += lo.x; acc[w * 4 + 1] += lo.y;
            acc[w * 4 + 2] += hi.x; acc[w * 4 + 3] += hi.y;
        }
    }
    #pragma unroll
    for (int e = 0; e < 8; ++e)
        acc[e] += __shfl_xor(acc[e], 32);

    const float inv = 1.0f / (float)KK;
    bf16x8 nv;
    #pragma unroll
    for (int e = 0; e < 8; ++e)
        nv[e] = (short)f2bf(acc[e] * inv);

    bf16x8 sv;
    sv[0] = (short)f2bf(s0.x); sv[1] = (short)f2bf(s0.y);
    sv[2] = (short)f2bf(s0.z); sv[3] = (short)f2bf(s0.w);
    sv[4] = (short)f2bf(s1.x); sv[5] = (short)f2bf(s1.y);
    sv[6] = (short)f2bf(s1.z); sv[7] = (short)f2bf(s1.w);

    const int tile = g >> 4, rr = g & 15;
    const int ks = l31 >> 2, kgw = l31 & 3;
    const size_t dst = (((size_t)(tile * 2 + sub) * 8 + ks) * 64 + kgw * 16 + rr) * 8;
    *(bf16x8*)&A[dst] = sub ? nv : sv;
}

__global__ __launch_bounds__(256, 4) void k_gemmf(
    const ushort* __restrict__ A,
    const ushort* __restrict__ WTf,
    const float*  __restrict__ bias,
    float*        __restrict__ out)
{
    const int wv   = __builtin_amdgcn_readfirstlane((int)(threadIdx.x >> 6));
    const int lane = threadIdx.x & 63;
    const int tile = blockIdx.x;
    const int half = wv >> 1, qt = wv & 1;
    const int r16 = lane & 15, kg = lane >> 4;

    bf16x8 a[8];
    #pragma unroll
    for (int ks = 0; ks < 8; ++ks)
        a[ks] = *(const bf16x8*)&A[(((size_t)(tile * 2 + half) * 8 + ks) * 64 + lane) * 8];

    f32x4 accs[8];
    #pragma unroll
    for (int ct = 0; ct < 8; ++ct) {
        const int t = qt * 8 + ct;
        f32x4 acc = {0.f, 0.f, 0.f, 0.f};
        #pragma unroll
        for (int ks = 0; ks < 8; ++ks) {
            const bf16x8 b = *(const bf16x8*)&WTf[(((size_t)(half * 16 + t) * 8 + ks) * 64 + lane) * 8];
            acc = __builtin_amdgcn_mfma_f32_16x16x32_bf16(a[ks], b, acc, 0, 0, 0);
        }
        accs[ct] = acc;
    }

    #pragma unroll
    for (int ct = 0; ct < 8; ++ct) {
        const int cglob = half * HH + (qt * 8 + ct) * 16 + r16;
        const float bv = bias[cglob];
        #pragma unroll
        for (int r = 0; r < 4; ++r) {
            const float v = accs[ct][r] + bv;
            out[(size_t)(tile * 16 + kg * 4 + r) * (2 * HH) + cglob] = v > 0.f ? v : 0.f;
        }
    }
}

// ------- last-resort fallback (round-1 fused fp32 kernel) ------------------
__global__ __launch_bounds__(256, 4) void hetegraph_fused_kernel(
    const float* __restrict__ embed, const int* __restrict__ node_ids,
    const int* __restrict__ nb_ids, const float* __restrict__ Ws,
    const float* __restrict__ Wn, const float* __restrict__ bias,
    float* __restrict__ out)
{
    __shared__ float As[BN][DD];
    __shared__ float An[BN][DD];
    const int tid = threadIdx.x, wave = tid >> 6, lane = tid & 63;
    const int g0 = blockIdx.x * BN;
    for (int n = wave; n < BN; n += 4) {
        const int g = g0 + n;
        const int self_row = node_ids[g];
        const float4 s = *(const float4*)&embed[(size_t)self_row * DD + lane * 4];
        float4 acc = make_float4(0.f, 0.f, 0.f, 0.f);
        for (int k0 = 0; k0 < KK; k0 += 8) {
            float4 r[8];
            #pragma unroll
            for (int j = 0; j < 8; ++j) {
                const int row = nb_ids[g * KK + k0 + j];
                r[j] = *(const float4*)&embed[(size_t)row * DD + lane * 4];
            }
            #pragma unroll
            for (int j = 0; j < 8; ++j) {
                acc.x += r[j].x; acc.y += r[j].y; acc.z += r[j].z; acc.w += r[j].w;
            }
        }
        const float inv = 1.0f / (float)KK;
        *(float4*)&As[n][lane * 4] = s;
        float4 m = make_float4(acc.x * inv, acc.y * inv, acc.z * inv, acc.w * inv);
        *(float4*)&An[n][lane * 4] = m;
    }
    __syncthreads();
    const int h = tid;
    {
        float acc[BN];
        #pragma unroll
        for (int n = 0; n < BN; ++n) acc[n] = 0.f;
        for (int d0 = 0; d0 < DD; d0 += 4) {
            const float w0 = Ws[(d0+0)*HH+h], w1 = Ws[(d0+1)*HH+h];
            const float w2 = Ws[(d0+2)*HH+h], w3 = Ws[(d0+3)*HH+h];
            #pragma unroll
            for (int n = 0; n < BN; ++n) {
                const float4 a = *(const float4*)&As[n][d0];
                acc[n] = fmaf(a.x,w0,acc[n]); acc[n] = fmaf(a.y,w1,acc[n]);
                acc[n] = fmaf(a.z,w2,acc[n]); acc[n] = fmaf(a.w,w3,acc[n]);
            }
        }
        const float b = bias[h];
        #pragma unroll
        for (int n = 0; n < BN; ++n) {
            const float v = acc[n] + b;
            out[(size_t)(g0+n)*(2*HH) + h] = v > 0.f ? v : 0.f;
        }
    }
    {
        float acc[BN];
        #pragma unroll
        for (int n = 0; n < BN; ++n) acc[n] = 0.f;
        for (int d0 = 0; d0 < DD; d0 += 4) {
            const float w0 = Wn[(d0+0)*HH+h], w1 = Wn[(d0+1)*HH+h];
            const float w2 = Wn[(d0+2)*HH+h], w3 = Wn[(d0+3)*HH+h];
            #pragma unroll
            for (int n = 0; n < BN; ++n) {
                const float4 a = *(const float4*)&An[n][d0];
                acc[n] = fmaf(a.x,w0,acc[n]); acc[n] = fmaf(a.y,w1,acc[n]);
                acc[n] = fmaf(a.z,w2,acc[n]); acc[n] = fmaf(a.w,w3,acc[n]);
            }
        }
        const float b = bias[HH + h];
        #pragma unroll
        for (int n = 0; n < BN; ++n) {
            const float v = acc[n] + b;
            out[(size_t)(g0+n)*(2*HH) + HH + h] = v > 0.f ? v : 0.f;
        }
    }
}

extern "C" void kernel_launch(void* const* d_in, const int* in_sizes, int n_in,
                              void* d_out, int out_size, void* d_ws, size_t ws_size,
                              hipStream_t stream) {
    const float* embed    = (const float*)d_in[0];
    const int*   node_ids = (const int*)d_in[1];
    const int*   nb_ids   = (const int*)d_in[2];
    const float* Ws       = (const float*)d_in[3];
    const float* Wn       = (const float*)d_in[4];
    const float* bias     = (const float*)d_in[5];
    float*       out      = (float*)d_out;

    const size_t e8_bytes  = (size_t)VV * DD;                              // 25.6 MB
    const size_t wt_bytes  = 2ull * HH * DD * sizeof(ushort);              // 256 KB
    const size_t wtf_bytes = 2ull * 16 * 8 * 64 * 8 * sizeof(ushort);      // 256 KB
    const size_t af_bytes  = (size_t)(NN / 16) * 2 * 8 * 64 * 8 * sizeof(ushort); // 20.48 MB

#if HAS_GLL
    if (ws_size >= e8_bytes + wt_bytes) {
        unsigned char* E8 = (unsigned char*)d_ws;
        ushort*        WT = (ushort*)((char*)d_ws + e8_bytes);
        k_prep_all<<<dim3(6250 + 32), dim3(256), 0, stream>>>(embed, E8, Ws, Wn, WT);
        k_fusedgl<<<dim3(NN / BN), dim3(256), 0, stream>>>(
            embed, E8, node_ids, nb_ids, WT, bias, out);
        return;
    }
#endif
    if (ws_size >= e8_bytes + wtf_bytes + af_bytes) {
        unsigned char* E8  = (unsigned char*)d_ws;
        ushort*        WTf = (ushort*)((char*)d_ws + e8_bytes);
        ushort*        Af  = (ushort*)((char*)d_ws + e8_bytes + wtf_bytes);
        k_prep_wf<<<dim3(16, 2), dim3(256), 0, stream>>>(Ws, Wn, WTf);
        k_conv8<<<dim3(VV * DD / 4096), dim3(256), 0, stream>>>(embed, E8);
        k_gather8<<<dim3(NN / 4), dim3(256), 0, stream>>>(embed, E8, node_ids, nb_ids, Af);
        k_gemmf<<<dim3(NN / 16), dim3(256), 0, stream>>>(Af, WTf, bias, out);
    } else {
        hetegraph_fused_kernel<<<dim3(NN / BN), dim3(256), 0, stream>>>(
            embed, node_ids, nb_ids, Ws, Wn, bias, out);
    }
}

// Round 13
// 93.260 us; speedup vs baseline: 1.0017x; 1.0017x over previous
//
#include <hip/hip_runtime.h>

#define VV 100000
#define NN 20000
#define KK 32
#define DD 256
#define HH 256
#define BN 16   // nodes per block in fused kernels

#if __has_builtin(__builtin_amdgcn_global_load_lds)
#define HAS_GLL 1
#else
#define HAS_GLL 0
#endif

typedef __attribute__((ext_vector_type(8))) short bf16x8;
typedef __attribute__((ext_vector_type(4))) float f32x4;
typedef __attribute__((ext_vector_type(2))) float f32x2;
typedef __attribute__((ext_vector_type(4))) uint  u32x4;
typedef __attribute__((ext_vector_type(2))) uint  u32x2;

__device__ __forceinline__ ushort f2bf(float f) {
    // round-to-nearest-even f32 -> bf16
    uint u = __float_as_uint(f);
    return (ushort)((u + 0x7FFFu + ((u >> 16) & 1u)) >> 16);
}
__device__ __forceinline__ float bf2f(ushort u) {
    return __uint_as_float(((uint)u) << 16);
}

// ------- Kernel 1 (merged): embed f32->fp8 table + W transpose to bf16 -----
// blocks [0,6250): conv8 (16 elems/thread); blocks [6250,6282): W prep.
__global__ __launch_bounds__(256) void k_prep_all(
    const float* __restrict__ E,  unsigned char* __restrict__ E8,
    const float* __restrict__ Ws, const float* __restrict__ Wn,
    ushort* __restrict__ WT)   // [2][H][D] bf16
{
    __shared__ float t[64][65];
    const int tid = threadIdx.x;
    const int bx  = blockIdx.x;

    if (bx < 6250) {
        const size_t i = ((size_t)bx * 256 + tid) * 16;
        u32x4 o;
        #pragma unroll
        for (int w = 0; w < 4; ++w) {
            const f32x4 a = __builtin_nontemporal_load((const f32x4*)&E[i + w * 4]);
            int r = 0;
            r = __builtin_amdgcn_cvt_pk_fp8_f32(a.x, a.y, r, false);
            r = __builtin_amdgcn_cvt_pk_fp8_f32(a.z, a.w, r, true);
            o[w] = (uint)r;
        }
        *(u32x4*)&E8[i] = o;
        return;
    }

    const int pb = bx - 6250;          // 0..31
    const int z  = pb >> 4;            // 0 = Ws, 1 = Wn
    const int rem = pb & 15;
    const int d0 = (rem & 3) * 64, h0 = (rem >> 2) * 64;
    const float* src = z ? Wn : Ws;
    ushort* dst = WT + (size_t)z * HH * DD;

    const int hl = tid & 63, dq = tid >> 6;
    #pragma unroll
    for (int i = 0; i < 16; ++i) {
        const int dl = dq * 16 + i;
        t[dl][hl] = src[(size_t)(d0 + dl) * HH + h0 + hl];
    }
    __syncthreads();
    const int dl = tid & 63, hq = tid >> 6;
    #pragma unroll
    for (int i = 0; i < 16; ++i) {
        const int h2 = hq * 16 + i;
        dst[(size_t)(h0 + h2) * DD + d0 + dl] = f2bf(t[dl][h2]);
    }
}

#if HAS_GLL
// ------- Kernel 2: fused gather (pipelined global_load_lds) + pool + GEMM --
// 256 thr = 4 waves, BN=16 nodes, grid 1250.
// Phase 1: 8 chunks/wave (4 nodes x 2 halves of 16 fp8 rows). Two 4-KB LDS
//   chunk regions per wave, double-buffered. COUNTED vmcnt(16) before pooling
//   chunk c keeps chunk c+1's 16 loads in flight (T4: never drain to 0 in the
//   loop) — this removes round-12's per-node drain serialization. The wait
//   invariant is robust to compiler-scheduled self-row loads: chunk c+1's 16
//   loads are always younger than chunk c, so "outstanding <= 16" implies
//   chunk c retired regardless of extra VMEM in the queue.
// Phase 2: byte-identical round-6 proven MFMA (half=wv>>1, colq=(wv&1)*128).
// LDS: stage 32 KB + As/An 16 KB = 48 KB -> 3 blocks/CU, 12 waves/CU.
__global__ __launch_bounds__(256, 3) void k_fusedgl(
    const float*         __restrict__ Ef,
    const unsigned char* __restrict__ E8,
    const int*           __restrict__ node_ids,
    const int*           __restrict__ nb_ids,
    const ushort*        __restrict__ WT,    // [2][H][D] bf16
    const float*         __restrict__ bias,  // [2H]
    float*               __restrict__ out)   // [N][2H]
{
    __shared__ unsigned char stage[4][2][16 * 256];  // 32 KB
    __shared__ ushort As[BN][DD];                    // 8 KB
    __shared__ ushort An[BN][DD];                    // 8 KB
    const int tid  = threadIdx.x;
    const int wv   = tid >> 6;
    const int lane = tid & 63;
    const int sub  = lane >> 5, l31 = lane & 31;
    const int g0   = blockIdx.x * BN;

    // self rows for this wave's 4 nodes, issued up-front (compiler-managed waits)
    f32x4 s0[4], s1[4];
    #pragma unroll
    for (int it = 0; it < 4; ++it) {
        const int srow = node_ids[g0 + wv + it * 4];   // uniform -> s_load
        s0[it] = *(const f32x4*)&Ef[(size_t)(uint)srow * DD + l31 * 8];
        s1[it] = *(const f32x4*)&Ef[(size_t)(uint)srow * DD + l31 * 8 + 4];
    }

    // chunk c (0..7): node it=c>>1, half h=c&1, rows [16h, 16h+16)
    auto issue = [&](int c) {
        const int it = c >> 1, h = c & 1;
        const int base = (g0 + wv + it * 4) * KK + h * 16;
        #pragma unroll
        for (int j = 0; j < 16; ++j) {
            const int row = nb_ids[base + j];          // uniform -> s_load
            const unsigned char* gp = E8 + (size_t)(uint)row * DD + lane * 4;
            __builtin_amdgcn_global_load_lds(
                (const __attribute__((address_space(1))) void*)gp,
                (__attribute__((address_space(3))) void*)&stage[wv][h][j * 256],
                4, 0, 0);
        }
    };

    issue(0);
    issue(1);

    float a0 = 0.f, a1 = 0.f, a2 = 0.f, a3 = 0.f;
    #pragma unroll
    for (int c = 0; c < 8; ++c) {
        if (c < 7) {
            asm volatile("s_waitcnt vmcnt(16)" ::: "memory");
        } else {
            asm volatile("s_waitcnt vmcnt(0)" ::: "memory");
        }
        __builtin_amdgcn_sched_barrier(0);

        const int h = c & 1;
        if (h == 0) { a0 = 0.f; a1 = 0.f; a2 = 0.f; a3 = 0.f; }
        #pragma unroll
        for (int j = 0; j < 16; ++j) {
            const uint w = *(const uint*)&stage[wv][h][j * 256 + lane * 4];
            const f32x2 lo = __builtin_amdgcn_cvt_pk_f32_fp8((int)w, false);
            const f32x2 hi = __builtin_amdgcn_cvt_pk_f32_fp8((int)w, true);
            a0 += lo.x; a1 += lo.y; a2 += hi.x; a3 += hi.y;
        }
        if (c + 2 < 8) issue(c + 2);   // after pool reads of region h complete

        if (h == 1) {
            const int it = c >> 1;
            const int n  = wv + it * 4;
            const float inv = 1.0f / (float)KK;
            const ushort4 nv = make_ushort4(f2bf(a0 * inv), f2bf(a1 * inv),
                                            f2bf(a2 * inv), f2bf(a3 * inv));
            const uint swz = ((uint)(n & 7)) << 4;
            *(ushort4*)((char*)&An[n][0] + ((((uint)lane) * 8) ^ swz)) = nv;
            if (sub == 0) {
                bf16x8 sv;
                sv[0] = (short)f2bf(s0[it].x); sv[1] = (short)f2bf(s0[it].y);
                sv[2] = (short)f2bf(s0[it].z); sv[3] = (short)f2bf(s0[it].w);
                sv[4] = (short)f2bf(s1[it].x); sv[5] = (short)f2bf(s1[it].y);
                sv[6] = (short)f2bf(s1[it].z); sv[7] = (short)f2bf(s1[it].w);
                *(bf16x8*)((char*)&As[n][0] + ((((uint)l31) * 16) ^ swz)) = sv;
            }
        }
    }
    __syncthreads();

    // ---- Phase 2 (round-6 proven) ----
    const int half = wv >> 1;
    const int colq = (wv & 1) * 128;
    const int r16  = lane & 15;
    const int kg   = lane >> 4;
    const uint rswz = ((uint)(r16 & 7)) << 4;
    const char* Arow = (const char*)(half ? &An[r16][0] : &As[r16][0]);

    bf16x8 a[8];
    #pragma unroll
    for (int ks = 0; ks < 8; ++ks) {
        const uint off = (uint)(ks * 64 + kg * 16);
        a[ks] = *(const bf16x8*)(Arow + (off ^ rswz));
    }

    const ushort* Wb = WT + (size_t)half * HH * DD;
    f32x4 accs[8];
    #pragma unroll
    for (int ct = 0; ct < 8; ++ct) {
        const int c = colq + ct * 16 + r16;
        const ushort* Bb = Wb + (size_t)c * DD + kg * 8;
        f32x4 acc = {0.f, 0.f, 0.f, 0.f};
        #pragma unroll
        for (int ks = 0; ks < 8; ++ks) {
            const bf16x8 b = *(const bf16x8*)(Bb + ks * 32);
            acc = __builtin_amdgcn_mfma_f32_16x16x32_bf16(a[ks], b, acc, 0, 0, 0);
        }
        accs[ct] = acc;
    }

    #pragma unroll
    for (int ct = 0; ct < 8; ++ct) {
        const int cglob = half * HH + colq + ct * 16 + r16;
        const float bv = bias[cglob];
        #pragma unroll
        for (int r = 0; r < 4; ++r) {
            const float v = accs[ct][r] + bv;
            out[(size_t)(g0 + kg * 4 + r) * (2 * HH) + cglob] = v > 0.f ? v : 0.f;
        }
    }
}
#endif  // HAS_GLL

// ===================== round-11 proven fallback pipeline ====================
__global__ __launch_bounds__(256) void k_conv8(
    const float* __restrict__ E, unsigned char* __restrict__ E8)
{
    const size_t i = ((size_t)blockIdx.x * 256 + threadIdx.x) * 16;
    u32x4 o;
    #pragma unroll
    for (int w = 0; w < 4; ++w) {
        const f32x4 a = __builtin_nontemporal_load((const f32x4*)&E[i + w * 4]);
        int r = 0;
        r = __builtin_amdgcn_cvt_pk_fp8_f32(a.x, a.y, r, false);
        r = __builtin_amdgcn_cvt_pk_fp8_f32(a.z, a.w, r, true);
        o[w] = (uint)r;
    }
    *(u32x4*)&E8[i] = o;
}

__global__ __launch_bounds__(256) void k_prep_wf(
    const float* __restrict__ Ws, const float* __restrict__ Wn,
    ushort* __restrict__ WTf)
{
    __shared__ float t[256][17];
    const int tid = threadIdx.x;
    const int h   = blockIdx.y;
    const int tt  = blockIdx.x;
    const float* src = h ? Wn : Ws;
    const int h0 = tt * 16;
    const int c = tid & 15, dr = tid >> 4;
    #pragma unroll
    for (int s = 0; s < 16; ++s) {
        const int d = s * 16 + dr;
        t[d][c] = src[(size_t)d * HH + h0 + c];
    }
    __syncthreads();
    const int fl = tid & 63, w = tid >> 6;
    const int r16 = fl & 15, kg = fl >> 4;
    #pragma unroll
    for (int p = 0; p < 2; ++p) {
        const int ks = w + p * 4;
        bf16x8 v;
        #pragma unroll
        for (int e = 0; e < 8; ++e)
            v[e] = (short)f2bf(t[ks * 32 + kg * 8 + e][r16]);
        *(bf16x8*)&WTf[(((size_t)(h * 16 + tt) * 8 + ks) * 64 + fl) * 8] = v;
    }
}

__global__ __launch_bounds__(256, 6) void k_gather8(
    const float*         __restrict__ Ef,
    const unsigned char* __restrict__ E8,
    const int*           __restrict__ node_ids,
    const int*           __restrict__ nb_ids,
    ushort*              __restrict__ A)
{
    const int wv   = threadIdx.x >> 6;
    const int lane = threadIdx.x & 63;
    const int sub  = lane >> 5, l31 = lane & 31;
    const int g    = blockIdx.x * 4 + wv;
    const int base = g * KK;

    const int srow = node_ids[g];
    const f32x4 s0 = *(const f32x4*)&Ef[(size_t)(uint)srow * DD + l31 * 8];
    const f32x4 s1 = *(const f32x4*)&Ef[(size_t)(uint)srow * DD + l31 * 8 + 4];

    u32x2 d[16];
    #pragma unroll
    for (int j = 0; j < 16; ++j) {
        const int rlo = nb_ids[base + 2 * j];
        const int rhi = nb_ids[base + 2 * j + 1];
        const int row = sub ? rhi : rlo;
        d[j] = *(const u32x2*)&E8[(size_t)(uint)row * DD + l31 * 8];
    }

    float acc[8];
    #pragma unroll
    for (int e = 0; e < 8; ++e) acc[e] = 0.f;
    #pragma unroll
    for (int j = 0; j < 16; ++j) {
        #pragma unroll
        for (int w = 0; w < 2; ++w) {
            const f32x2 lo = __builtin_amdgcn_cvt_pk_f32_fp8((int)d[j][w], false);
            const f32x2 hi = __builtin_amdgcn_cvt_pk_f32_fp8((int)d[j][w], true);
            acc[w * 4 + 0] += lo.x; acc[w * 4 + 1] += lo.y;
            acc[w * 4 + 2] += hi.x; acc[w * 4 + 3] += hi.y;
        }
    }
    #pragma unroll
    for (int e = 0; e < 8; ++e)
        acc[e] += __shfl_xor(acc[e], 32);

    const float inv = 1.0f / (float)KK;
    bf16x8 nv;
    #pragma unroll
    for (int e = 0; e < 8; ++e)
        nv[e] = (short)f2bf(acc[e] * inv);

    bf16x8 sv;
    sv[0] = (short)f2bf(s0.x); sv[1] = (short)f2bf(s0.y);
    sv[2] = (short)f2bf(s0.z); sv[3] = (short)f2bf(s0.w);
    sv[4] = (short)f2bf(s1.x); sv[5] = (short)f2bf(s1.y);
    sv[6] = (short)f2bf(s1.z); sv[7] = (short)f2bf(s1.w);

    const int tile = g >> 4, rr = g & 15;
    const int ks = l31 >> 2, kgw = l31 & 3;
    const size_t dst = (((size_t)(tile * 2 + sub) * 8 + ks) * 64 + kgw * 16 + rr) * 8;
    *(bf16x8*)&A[dst] = sub ? nv : sv;
}

__global__ __launch_bounds__(256, 4) void k_gemmf(
    const ushort* __restrict__ A,
    const ushort* __restrict__ WTf,
    const float*  __restrict__ bias,
    float*        __restrict__ out)
{
    const int wv   = __builtin_amdgcn_readfirstlane((int)(threadIdx.x >> 6));
    const int lane = threadIdx.x & 63;
    const int tile = blockIdx.x;
    const int half = wv >> 1, qt = wv & 1;
    const int r16 = lane & 15, kg = lane >> 4;

    bf16x8 a[8];
    #pragma unroll
    for (int ks = 0; ks < 8; ++ks)
        a[ks] = *(const bf16x8*)&A[(((size_t)(tile * 2 + half) * 8 + ks) * 64 + lane) * 8];

    f32x4 accs[8];
    #pragma unroll
    for (int ct = 0; ct < 8; ++ct) {
        const int t = qt * 8 + ct;
        f32x4 acc = {0.f, 0.f, 0.f, 0.f};
        #pragma unroll
        for (int ks = 0; ks < 8; ++ks) {
            const bf16x8 b = *(const bf16x8*)&WTf[(((size_t)(half * 16 + t) * 8 + ks) * 64 + lane) * 8];
            acc = __builtin_amdgcn_mfma_f32_16x16x32_bf16(a[ks], b, acc, 0, 0, 0);
        }
        accs[ct] = acc;
    }

    #pragma unroll
    for (int ct = 0; ct < 8; ++ct) {
        const int cglob = half * HH + (qt * 8 + ct) * 16 + r16;
        const float bv = bias[cglob];
        #pragma unroll
        for (int r = 0; r < 4; ++r) {
            const float v = accs[ct][r] + bv;
            out[(size_t)(tile * 16 + kg * 4 + r) * (2 * HH) + cglob] = v > 0.f ? v : 0.f;
        }
    }
}

// ------- last-resort fallback (round-1 fused fp32 kernel) ------------------
__global__ __launch_bounds__(256, 4) void hetegraph_fused_kernel(
    const float* __restrict__ embed, const int* __restrict__ node_ids,
    const int* __restrict__ nb_ids, const float* __restrict__ Ws,
    const float* __restrict__ Wn, const float* __restrict__ bias,
    float* __restrict__ out)
{
    __shared__ float As[BN][DD];
    __shared__ float An[BN][DD];
    const int tid = threadIdx.x, wave = tid >> 6, lane = tid & 63;
    const int g0 = blockIdx.x * BN;
    for (int n = wave; n < BN; n += 4) {
        const int g = g0 + n;
        const int self_row = node_ids[g];
        const float4 s = *(const float4*)&embed[(size_t)self_row * DD + lane * 4];
        float4 acc = make_float4(0.f, 0.f, 0.f, 0.f);
        for (int k0 = 0; k0 < KK; k0 += 8) {
            float4 r[8];
            #pragma unroll
            for (int j = 0; j < 8; ++j) {
                const int row = nb_ids[g * KK + k0 + j];
                r[j] = *(const float4*)&embed[(size_t)row * DD + lane * 4];
            }
            #pragma unroll
            for (int j = 0; j < 8; ++j) {
                acc.x += r[j].x; acc.y += r[j].y; acc.z += r[j].z; acc.w += r[j].w;
            }
        }
        const float inv = 1.0f / (float)KK;
        *(float4*)&As[n][lane * 4] = s;
        float4 m = make_float4(acc.x * inv, acc.y * inv, acc.z * inv, acc.w * inv);
        *(float4*)&An[n][lane * 4] = m;
    }
    __syncthreads();
    const int h = tid;
    {
        float acc[BN];
        #pragma unroll
        for (int n = 0; n < BN; ++n) acc[n] = 0.f;
        for (int d0 = 0; d0 < DD; d0 += 4) {
            const float w0 = Ws[(d0+0)*HH+h], w1 = Ws[(d0+1)*HH+h];
            const float w2 = Ws[(d0+2)*HH+h], w3 = Ws[(d0+3)*HH+h];
            #pragma unroll
            for (int n = 0; n < BN; ++n) {
                const float4 a = *(const float4*)&As[n][d0];
                acc[n] = fmaf(a.x,w0,acc[n]); acc[n] = fmaf(a.y,w1,acc[n]);
                acc[n] = fmaf(a.z,w2,acc[n]); acc[n] = fmaf(a.w,w3,acc[n]);
            }
        }
        const float b = bias[h];
        #pragma unroll
        for (int n = 0; n < BN; ++n) {
            const float v = acc[n] + b;
            out[(size_t)(g0+n)*(2*HH) + h] = v > 0.f ? v : 0.f;
        }
    }
    {
        float acc[BN];
        #pragma unroll
        for (int n = 0; n < BN; ++n) acc[n] = 0.f;
        for (int d0 = 0; d0 < DD; d0 += 4) {
            const float w0 = Wn[(d0+0)*HH+h], w1 = Wn[(d0+1)*HH+h];
            const float w2 = Wn[(d0+2)*HH+h], w3 = Wn[(d0+3)*HH+h];
            #pragma unroll
            for (int n = 0; n < BN; ++n) {
                const float4 a = *(const float4*)&An[n][d0];
                acc[n] = fmaf(a.x,w0,acc[n]); acc[n] = fmaf(a.y,w1,acc[n]);
                acc[n] = fmaf(a.z,w2,acc[n]); acc[n] = fmaf(a.w,w3,acc[n]);
            }
        }
        const float b = bias[HH + h];
        #pragma unroll
        for (int n = 0; n < BN; ++n) {
            const float v = acc[n] + b;
            out[(size_t)(g0+n)*(2*HH) + HH + h] = v > 0.f ? v : 0.f;
        }
    }
}

extern "C" void kernel_launch(void* const* d_in, const int* in_sizes, int n_in,
                              void* d_out, int out_size, void* d_ws, size_t ws_size,
                              hipStream_t stream) {
    const float* embed    = (const float*)d_in[0];
    const int*   node_ids = (const int*)d_in[1];
    const int*   nb_ids   = (const int*)d_in[2];
    const float* Ws       = (const float*)d_in[3];
    const float* Wn       = (const float*)d_in[4];
    const float* bias     = (const float*)d_in[5];
    float*       out      = (float*)d_out;

    const size_t e8_bytes  = (size_t)VV * DD;                              // 25.6 MB
    const size_t wt_bytes  = 2ull * HH * DD * sizeof(ushort);              // 256 KB
    const size_t wtf_bytes = 2ull * 16 * 8 * 64 * 8 * sizeof(ushort);      // 256 KB
    const size_t af_bytes  = (size_t)(NN / 16) * 2 * 8 * 64 * 8 * sizeof(ushort); // 20.48 MB

#if HAS_GLL
    if (ws_size >= e8_bytes + wt_bytes) {
        unsigned char* E8 = (unsigned char*)d_ws;
        ushort*        WT = (ushort*)((char*)d_ws + e8_bytes);
        k_prep_all<<<dim3(6250 + 32), dim3(256), 0, stream>>>(embed, E8, Ws, Wn, WT);
        k_fusedgl<<<dim3(NN / BN), dim3(256), 0, stream>>>(
            embed, E8, node_ids, nb_ids, WT, bias, out);
        return;
    }
#endif
    if (ws_size >= e8_bytes + wtf_bytes + af_bytes) {
        unsigned char* E8  = (unsigned char*)d_ws;
        ushort*        WTf = (ushort*)((char*)d_ws + e8_bytes);
        ushort*        Af  = (ushort*)((char*)d_ws + e8_bytes + wtf_bytes);
        k_prep_wf<<<dim3(16, 2), dim3(256), 0, stream>>>(Ws, Wn, WTf);
        k_conv8<<<dim3(VV * DD / 4096), dim3(256), 0, stream>>>(embed, E8);
        k_gather8<<<dim3(NN / 4), dim3(256), 0, stream>>>(embed, E8, node_ids, nb_ids, Af);
        k_gemmf<<<dim3(NN / 16), dim3(256), 0, stream>>>(Af, WTf, bias, out);
    } else {
        hetegraph_fused_kernel<<<dim3(NN / BN), dim3(256), 0, stream>>>(
            embed, node_ids, nb_ids, Ws, Wn, bias, out);
    }
}